// Round 1
// baseline (77512.115 us; speedup 1.0000x reference)
//
#include <hip/hip_runtime.h>

// ScaledODENetFE: forward-Euler scan, T=44100 steps, B=32, F=1, S=16, H=64.
// One wave (64 lanes) per batch element; lane j owns hidden unit j.
// y[16] replicated across lanes -> first matmul is lane-local FMAs;
// second matmul reduced with a full xor-butterfly so all lanes get all 16 sums.

#define SRATE 44100.0f
#define T_TOTAL 44100
#define BATCH 32
#define HID 64
#define ST 16

__global__ __launch_bounds__(64, 1)
void ScaledODENetFE_kernel(const float* __restrict__ x,
                           const float* __restrict__ W1,
                           const float* __restrict__ b1,
                           const float* __restrict__ W2,
                           const float* __restrict__ b2v,
                           float* __restrict__ out) {
    const int b = blockIdx.x;      // batch element
    const int lane = threadIdx.x;  // hidden unit j
    const int TM1 = T_TOTAL - 1;   // 44099 scan steps

    // Per-lane weights (lane j): W1 is (1+ST, HID) row-major, W2 is (HID, ST).
    float w1x = W1[lane];          // W1[0][j] (input feature column)
    float w1y[ST], w2[ST], bb2[ST];
    #pragma unroll
    for (int s = 0; s < ST; ++s) {
        w1y[s] = W1[(1 + s) * HID + lane];
        w2[s]  = W2[lane * ST + s];
        bb2[s] = b2v[s];
    }
    float bb1 = b1[lane];

    // Replicated carry: y and y/sr (state starts at zeros).
    float y[ST], ydiv[ST];
    #pragma unroll
    for (int s = 0; s < ST; ++s) { y[s] = 0.f; ydiv[s] = 0.f; }

    // Row t=0 of the output is zeros.
    if (lane == 0) out[b] = 0.f;

    // Preload first x chunk: lane l holds x[(t0+l)*B + b].
    float xv = x[min(lane, TM1 - 1) * BATCH + b];

    for (int t0 = 0; t0 < TM1; t0 += 64) {
        // Prefetch next chunk (clamped in-bounds; value unused past the end).
        int tn = t0 + 64 + lane;
        float xv_next = x[min(tn, TM1 - 1) * BATCH + b];

        const int nsteps = min(64, TM1 - t0);
        float outv = 0.f;

        for (int k = 0; k < nsteps; ++k) {
            // Broadcast this step's input sample to all lanes.
            float xt = __shfl(xv, k);

            // Hidden pre-activation: inp @ W1 (+ b1 after, matching ref order).
            float acc = xt * w1x;
            #pragma unroll
            for (int s = 0; s < ST; ++s) acc = fmaf(ydiv[s], w1y[s], acc);
            acc += bb1;
            float h = tanhf(acc);

            // Second matmul partials, then butterfly all-reduce over 64 lanes.
            float p[ST];
            #pragma unroll
            for (int s = 0; s < ST; ++s) p[s] = h * w2[s];
            #pragma unroll
            for (int off = 32; off >= 1; off >>= 1) {
                #pragma unroll
                for (int s = 0; s < ST; ++s) p[s] += __shfl_xor(p[s], off);
            }

            // Euler update (fp32, same op order as reference).
            #pragma unroll
            for (int s = 0; s < ST; ++s) {
                float d = p[s] + bb2[s];
                y[s] = y[s] + d;
                ydiv[s] = y[s] / SRATE;   // IEEE div, matches ref's y/sr
            }

            // Lane k keeps this step's output (y1/sr, feature 0).
            outv = (k == lane) ? ydiv[0] : outv;
        }

        // Coalesced chunk store: step t0+l -> out[(t0+l+1)*B + b].
        if (lane < nsteps) out[(t0 + 1 + lane) * BATCH + b] = outv;

        xv = xv_next;
    }
}

extern "C" void kernel_launch(void* const* d_in, const int* in_sizes, int n_in,
                              void* d_out, int out_size, void* d_ws, size_t ws_size,
                              hipStream_t stream) {
    const float* x  = (const float*)d_in[0];
    const float* W1 = (const float*)d_in[1];
    const float* b1 = (const float*)d_in[2];
    const float* W2 = (const float*)d_in[3];
    const float* b2 = (const float*)d_in[4];
    float* out = (float*)d_out;

    ScaledODENetFE_kernel<<<BATCH, 64, 0, stream>>>(x, W1, b1, W2, b2, out);
}

// Round 2
// 35019.388 us; speedup vs baseline: 2.2134x; 2.2134x over previous
//
#include <hip/hip_runtime.h>

// ScaledODENetFE: forward-Euler scan, T=44100, B=32, F=1, S=16, H=64.
// One wave per batch element; lane j owns hidden unit j. Latency-bound:
// wall time = 44099 x per-step critical path. This version removes all
// DS ops and divisions from the chain:
//  - second-matmul reduction via DPP v_add (row_shr 1/2/4/8, row_bcast 15/31)
//    + v_readlane(63) -> wave-uniform sum in SGPR (no ds_swizzle).
//  - 1/sr folded into W1 state columns at init (one-time IEEE div), so the
//    carry is unscaled y and the 16 per-step divisions disappear.
//  - output y[0]/sr computed as ONE vector IEEE division per 64-step chunk.
//  - x broadcast via readlane (SGPR) instead of ds_bpermute.
//  - first matmul as 4 parallel FMA chains (tree combine).

#define SRATE 44100.0f
#define T_TOTAL 44100
#define BATCH 32
#define ST 16

template <int CTRL, int RM>
__device__ __forceinline__ float dpp_add(float x) {
    int t = __builtin_amdgcn_update_dpp(0, __builtin_bit_cast(int, x),
                                        CTRL, RM, 0xF, false);
    return x + __builtin_bit_cast(float, t);
}

// Full 64-lane sum -> wave-uniform scalar (result read from lane 63).
__device__ __forceinline__ float wave_sum(float x) {
    x = dpp_add<0x111, 0xF>(x);  // row_shr:1
    x = dpp_add<0x112, 0xF>(x);  // row_shr:2
    x = dpp_add<0x114, 0xF>(x);  // row_shr:4
    x = dpp_add<0x118, 0xF>(x);  // row_shr:8  -> lane 15 of each row = row sum
    x = dpp_add<0x142, 0xA>(x);  // row_bcast:15 -> lane31=sum(0:31), lane63=sum(32:63)
    x = dpp_add<0x143, 0xC>(x);  // row_bcast:31 -> lane63=sum(0:63)
    return __builtin_bit_cast(float,
        __builtin_amdgcn_readlane(__builtin_bit_cast(int, x), 63));
}

__global__ __launch_bounds__(64, 1)
void ScaledODENetFE_kernel(const float* __restrict__ x,
                           const float* __restrict__ W1,
                           const float* __restrict__ b1,
                           const float* __restrict__ W2,
                           const float* __restrict__ b2v,
                           float* __restrict__ out) {
    const int b = blockIdx.x;      // batch element
    const int lane = threadIdx.x;  // hidden unit j
    const int TM1 = T_TOTAL - 1;   // 44099 scan steps

    // Lane-j weights. W1 is (1+ST, HID) row-major; W2 is (HID, ST).
    float w1x = W1[lane];
    float w1yd[ST], w2[ST], bb2[ST];
    #pragma unroll
    for (int s = 0; s < ST; ++s) {
        w1yd[s] = W1[(1 + s) * 64 + lane] / SRATE;  // fold 1/sr (one-time IEEE div)
        w2[s]   = W2[lane * ST + s];
        bb2[s]  = b2v[s];
    }
    float bb1 = b1[lane];

    // Wave-uniform unscaled carry y.
    float y[ST];
    #pragma unroll
    for (int s = 0; s < ST; ++s) y[s] = 0.f;

    if (lane == 0) out[b] = 0.f;   // row t=0 is zeros

    // Lane l holds x[(t0+l)*B + b]; prefetch one chunk ahead.
    float xv = x[min(lane, TM1 - 1) * BATCH + b];

    for (int t0 = 0; t0 < TM1; t0 += 64) {
        float xv_next = x[min(t0 + 64 + lane, TM1 - 1) * BATCH + b];
        const int nsteps = min(64, TM1 - t0);
        float outy = 0.f;          // lane k captures y[0] after step t0+k

        for (int k = 0; k < nsteps; ++k) {
            // Wave-uniform input sample (SGPR, no DS op).
            float xt = __builtin_bit_cast(float,
                __builtin_amdgcn_readlane(__builtin_bit_cast(int, xv), k));

            // First matmul: 4 parallel FMA chains, tree combine.
            float a0 = xt * w1x;
            float a1 = y[4] * w1yd[4];
            float a2 = y[8] * w1yd[8];
            float a3 = y[12] * w1yd[12];
            #pragma unroll
            for (int s = 0; s < 4; ++s)  a0 = fmaf(y[s], w1yd[s], a0);
            #pragma unroll
            for (int s = 5; s < 8; ++s)  a1 = fmaf(y[s], w1yd[s], a1);
            #pragma unroll
            for (int s = 9; s < 12; ++s) a2 = fmaf(y[s], w1yd[s], a2);
            #pragma unroll
            for (int s = 13; s < 16; ++s) a3 = fmaf(y[s], w1yd[s], a3);
            float h = tanhf(((a0 + a1) + (a2 + a3)) + bb1);

            // Second matmul: per-lane partials, DPP wave-reduce each state dim.
            #pragma unroll
            for (int s = 0; s < ST; ++s) {
                float S = wave_sum(h * w2[s]);
                float d = S + bb2[s];   // reference op order: (p + b2), then y + d
                y[s] = y[s] + d;
            }

            // Lane k keeps this step's y[0] (scaled & stored after the chunk).
            outy = (k == lane) ? y[0] : outy;
        }

        // One vector IEEE division per chunk, then coalesced store.
        if (lane < nsteps) out[(t0 + 1 + lane) * BATCH + b] = outy / SRATE;

        xv = xv_next;
    }
}

extern "C" void kernel_launch(void* const* d_in, const int* in_sizes, int n_in,
                              void* d_out, int out_size, void* d_ws, size_t ws_size,
                              hipStream_t stream) {
    const float* x  = (const float*)d_in[0];
    const float* W1 = (const float*)d_in[1];
    const float* b1 = (const float*)d_in[2];
    const float* W2 = (const float*)d_in[3];
    const float* b2 = (const float*)d_in[4];
    float* out = (float*)d_out;

    ScaledODENetFE_kernel<<<BATCH, 64, 0, stream>>>(x, W1, b1, W2, b2, out);
}

// Round 3
// 12334.718 us; speedup vs baseline: 6.2841x; 2.8391x over previous
//
#include <hip/hip_runtime.h>

// ScaledODENetFE: forward-Euler scan, T=44100, B=32, F=1, S=16, H=64.
// One wave per batch; lane j owns hidden unit j. Issue-count-bound
// (VALUBusy 2.0% vs 3.1% ceiling at 32 waves). R2: collapse the recurrence.
//
//   v_j = b1_j + sum_s y_s * (W1[1+s,j]/sr)   (tanh pre-activation, sans x)
//   h   = tanh(v + x_t * W1[0,:])
//   v' = v + c + M^T h,  M[k,j] = sum_s W2[k,s]*W1[1+s,j]/sr  (precomputed)
//   y0' = y0 + (sum_k h_k W2[k,0] + b2[0])    (only state dim 0 is output)
//
// Removes the 17-FMA first matmul, 15/16 wave-reductions, 30/32 update ops.
// Matvec M^T h done as 64x (v_readlane -> SGPR) + v_fma with SGPR operand.
// Custom tanh: (t-1)/(t+1), t=exp2(2z*log2e), Newton-refined v_rcp (~10 ops).
// Output error from h perturbations is attenuated by 1/sr -> negligible;
// y0's accumulation keeps the exact reference op order.

#define SRATE 44100.0f
#define T_TOTAL 44100
#define BATCH 32
#define HID 64
#define ST 16

template <int CTRL, int RM>
__device__ __forceinline__ float dpp_add(float x) {
    int t = __builtin_amdgcn_update_dpp(0, __builtin_bit_cast(int, x),
                                        CTRL, RM, 0xF, false);
    return x + __builtin_bit_cast(float, t);
}

// Full 64-lane sum -> wave-uniform scalar (read from lane 63).
__device__ __forceinline__ float wave_sum(float x) {
    x = dpp_add<0x111, 0xF>(x);  // row_shr:1
    x = dpp_add<0x112, 0xF>(x);  // row_shr:2
    x = dpp_add<0x114, 0xF>(x);  // row_shr:4
    x = dpp_add<0x118, 0xF>(x);  // row_shr:8
    x = dpp_add<0x142, 0xA>(x);  // row_bcast:15
    x = dpp_add<0x143, 0xC>(x);  // row_bcast:31
    return __builtin_bit_cast(float,
        __builtin_amdgcn_readlane(__builtin_bit_cast(int, x), 63));
}

__device__ __forceinline__ float bcast(float v, int lane) {
    return __builtin_bit_cast(float,
        __builtin_amdgcn_readlane(__builtin_bit_cast(int, v), lane));
}

// tanh(z) = (e^{2z}-1)/(e^{2z}+1); |z| clamp only guards exp overflow
// (formula already yields exactly 1.0f for z>~9). ~10 ops, chain ~60 cyc.
__device__ __forceinline__ float fast_tanh(float z) {
    z = __builtin_amdgcn_fmed3f(z, -30.f, 30.f);
    float t = __builtin_amdgcn_exp2f(z * 2.8853900817779268f); // 2*log2(e)
    float den = t + 1.f;
    float num = t - 1.f;
    float r = __builtin_amdgcn_rcpf(den);
    r = r * fmaf(-den, r, 2.f);   // one Newton step -> ~0.5 ulp division
    return num * r;
}

__global__ __launch_bounds__(64, 1)
void ScaledODENetFE_kernel(const float* __restrict__ x,
                           const float* __restrict__ W1,
                           const float* __restrict__ b1,
                           const float* __restrict__ W2,
                           const float* __restrict__ b2v,
                           float* __restrict__ out) {
    const int b = blockIdx.x;      // batch element
    const int lane = threadIdx.x;  // hidden unit j
    const int TM1 = T_TOTAL - 1;   // 44099 scan steps

    // ---- one-time precompute (lane j) ----
    float w1x = W1[lane];                       // W1[0][j]
    float w1yd[ST];
    #pragma unroll
    for (int s = 0; s < ST; ++s)
        w1yd[s] = W1[(1 + s) * HID + lane] / SRATE;

    float c = 0.f;                              // c_j = sum_s b2[s]*w1yd[s]
    #pragma unroll
    for (int s = 0; s < ST; ++s) c = fmaf(b2v[s], w1yd[s], c);

    float m[HID];                               // M[k][j], 64 VGPRs
    #pragma unroll
    for (int k = 0; k < HID; ++k) {
        float acc = 0.f;
        #pragma unroll
        for (int s = 0; s < ST; ++s) acc = fmaf(W2[k * ST + s], w1yd[s], acc);
        m[k] = acc;
    }

    float w2c0 = W2[lane * ST];                 // W2[j][0]
    float b20  = b2v[0];

    float v  = b1[lane];                        // v carries b1 (y starts 0)
    float y0 = 0.f;

    if (lane == 0) out[b] = 0.f;                // row t=0 is zeros

    // Lane l holds x[(t0+l)*B + b]; prefetch one chunk ahead.
    float xv = x[min(lane, TM1 - 1) * BATCH + b];

    for (int t0 = 0; t0 < TM1; t0 += 64) {
        float xv_next = x[min(t0 + 64 + lane, TM1 - 1) * BATCH + b];
        const int nsteps = min(64, TM1 - t0);
        float outy = 0.f;

        for (int kk = 0; kk < nsteps; ++kk) {
            float xt = bcast(xv, kk);           // wave-uniform sample
            float z  = fmaf(xt, w1x, v);
            float h  = fast_tanh(z);

            // y0 path (reference op order: d0 = S0 + b2[0]; y0 += d0).
            float S0 = wave_sum(h * w2c0);
            y0 += S0 + b20;
            outy = (kk == lane) ? y0 : outy;

            // v update: r_j = sum_k h_k * M[k][j] via SGPR-broadcast FMAs.
            float r0 = 0.f, r1 = 0.f, r2 = 0.f, r3 = 0.f;
            #pragma unroll
            for (int q = 0; q < HID; q += 4) {
                r0 = fmaf(bcast(h, q + 0), m[q + 0], r0);
                r1 = fmaf(bcast(h, q + 1), m[q + 1], r1);
                r2 = fmaf(bcast(h, q + 2), m[q + 2], r2);
                r3 = fmaf(bcast(h, q + 3), m[q + 3], r3);
            }
            v = v + c + ((r0 + r1) + (r2 + r3));
        }

        // One vector IEEE division per chunk, coalesced store.
        if (lane < nsteps) out[(t0 + 1 + lane) * BATCH + b] = outy / SRATE;

        xv = xv_next;
    }
}

extern "C" void kernel_launch(void* const* d_in, const int* in_sizes, int n_in,
                              void* d_out, int out_size, void* d_ws, size_t ws_size,
                              hipStream_t stream) {
    const float* x  = (const float*)d_in[0];
    const float* W1 = (const float*)d_in[1];
    const float* b1 = (const float*)d_in[2];
    const float* W2 = (const float*)d_in[3];
    const float* b2 = (const float*)d_in[4];
    float* out = (float*)d_out;

    ScaledODENetFE_kernel<<<BATCH, 64, 0, stream>>>(x, W1, b1, W2, b2, out);
}

// Round 4
// 8994.925 us; speedup vs baseline: 8.6173x; 1.3713x over previous
//
#include <hip/hip_runtime.h>

// ScaledODENetFE: forward-Euler scan, T=44100, B=32, F=1, S=16, H=64.
// One wave per batch; lane k owns hidden unit k. Issue-bound (~2 cyc/VALU op,
// 32 waves on 256 CUs). R3: exploit rank(M)=16 of the collapsed recurrence:
//   p = W2^T h  (16 sums over 64 lanes)  -> butterfly reduce-scatter
//   r = (W1[1:]/sr)^T p                  -> 16 readlane-bcast + 16 FMA
//   v' = v + c + r;  y0 += (p_0 + b2[0]) (p_0 free from the scatter)
//
// Reduce-scatter is positionally uniform: lane k stores its W2 row PERMUTED
// (dual-basis bookkeeping over XOR generators g1..g4 = 1,2,7,8) so every
// stage is "u[i] += dpp_exchange(u[i+half])" with identical code in all
// lanes; lane k ends holding p_{k mod 16}. Generators map to cheap DPP:
//   xor1 = quad_perm[1,0,3,2] (0xB1), xor2 = quad_perm[2,3,0,1] (0x4E),
//   xor7 = row_half_mirror (0x141),   xor8 = row_ror:8 (0x128).
// Cross-row: xor16 = ds_swizzle 0x401F, xor32 = ds_bpermute (precomp addr).
// Stage 1 fuses the h*W2 products using the xor1-partner's weights (wB).
// ~83 VALU ops/step vs R2's ~160. tanh: rcp without Newton (h noise is
// invisible vs ulp(y0) — absmax was bit-identical across R1/R2 numerics).

#define SRATE 44100.0f
#define T_TOTAL 44100
#define BATCH 32
#define HID 64
#define ST 16

template <int CTRL>
__device__ __forceinline__ float dppmov(float x) {
    return __builtin_bit_cast(float,
        __builtin_amdgcn_update_dpp(0, __builtin_bit_cast(int, x),
                                    CTRL, 0xF, 0xF, false));
}

__device__ __forceinline__ float bcast(float v, int lane) {
    return __builtin_bit_cast(float,
        __builtin_amdgcn_readlane(__builtin_bit_cast(int, v), lane));
}

// tanh(z) = (t-1)/(t+1), t = 2^(2z*log2e). rcp ~1 ulp, no Newton.
__device__ __forceinline__ float fast_tanh(float z) {
    z = __builtin_amdgcn_fmed3f(z, -30.f, 30.f);
    float t = __builtin_amdgcn_exp2f(z * 2.8853900817779268f);
    float r = __builtin_amdgcn_rcpf(t + 1.f);
    return (t - 1.f) * r;
}

__device__ __forceinline__ int parity(int v) { return __builtin_popcount(v) & 1; }

__global__ __launch_bounds__(64, 1)
void ScaledODENetFE_kernel(const float* __restrict__ x,
                           const float* __restrict__ W1,
                           const float* __restrict__ b1,
                           const float* __restrict__ W2,
                           const float* __restrict__ b2v,
                           float* __restrict__ out) {
    const int b = blockIdx.x;      // batch element
    const int lane = threadIdx.x;  // hidden unit k
    const int TM1 = T_TOTAL - 1;   // 44099 scan steps

    // ---- one-time precompute (lane k) ----
    float w1x = W1[lane];                       // W1[0][k]
    float w1yd[ST];
    #pragma unroll
    for (int s = 0; s < ST; ++s)
        w1yd[s] = W1[(1 + s) * HID + lane] / SRATE;

    float c = 0.f;                              // c_k = sum_s b2[s]*w1yd[s]
    #pragma unroll
    for (int s = 0; s < ST; ++s) c = fmaf(b2v[s], w1yd[s], c);

    // Dual-basis lane phis for the permuted W2 layout.
    const int p1 = parity(lane & 5), p2 = parity(lane & 6);
    const int p3 = (lane >> 2) & 1, p4 = (lane >> 3) & 1;
    // Slot i (i = t1 | t2<<1 | t3<<2 | t4<<3) holds s(k,i):
    //   c_j = t_j ^ phi_j(k);  s = (c1?1:0)^(c2?2:0)^(c3?7:0)^(c4?8:0)
    float wA[8], wB[8];   // own row / xor1-partner row, at even slots i=2j
    #pragma unroll
    for (int j = 0; j < 8; ++j) {
        const int i = 2 * j;
        const int c1 = (i & 1) ^ p1;
        const int c2 = ((i >> 1) & 1) ^ p2;
        const int c3 = ((i >> 2) & 1) ^ p3;
        const int c4 = ((i >> 3) & 1) ^ p4;
        const int s = (c1 ? 1 : 0) ^ (c2 ? 2 : 0) ^ (c3 ? 7 : 0) ^ (c4 ? 8 : 0);
        wA[j] = W2[lane * ST + s];
        wB[j] = W2[(lane ^ 1) * ST + s];
    }

    const int bp32 = ((lane ^ 32) & 63) << 2;   // ds_bpermute byte addr (xor32)
    float b20v = b2v[0];

    float v  = b1[lane];                        // v carries b1 (y starts 0)
    float y0 = 0.f;

    if (lane == 0) out[b] = 0.f;                // row t=0 is zeros

    // Lane l holds x[(t0+l)*B + b]; prefetch one chunk ahead.
    float xv = x[min(lane, TM1 - 1) * BATCH + b];

    for (int t0 = 0; t0 < TM1; t0 += 64) {
        float xv_next = x[min(t0 + 64 + lane, TM1 - 1) * BATCH + b];
        const int nsteps = min(64, TM1 - t0);
        float outy = 0.f;

        for (int kk = 0; kk < nsteps; ++kk) {
            float xt = bcast(xv, kk);           // wave-uniform sample
            float z  = fmaf(xt, w1x, v);
            float h  = fast_tanh(z);

            // Stage 1 (xor1, fused products): u1[j] = h*wA[j] + h_partner*wB[j]
            float hx = dppmov<0xB1>(h);         // quad_perm [1,0,3,2]
            float u1[8];
            #pragma unroll
            for (int j = 0; j < 8; ++j) u1[j] = fmaf(hx, wB[j], h * wA[j]);

            // Stage 2 (xor2): keep even slots, add partner's odd slots.
            float u2[4];
            #pragma unroll
            for (int m = 0; m < 4; ++m)
                u2[m] = u1[2 * m] + dppmov<0x4E>(u1[2 * m + 1]);

            // Stage 3 (xor7 = row_half_mirror).
            float u3[2];
            #pragma unroll
            for (int n = 0; n < 2; ++n)
                u3[n] = u2[2 * n] + dppmov<0x141>(u2[2 * n + 1]);

            // Stage 4 (xor8 = row_ror:8).
            float P = u3[0] + dppmov<0x128>(u3[1]);

            // Cross-row: xor16 (ds_swizzle), xor32 (ds_bpermute).
            P += __builtin_bit_cast(float,
                 __builtin_amdgcn_ds_swizzle(__builtin_bit_cast(int, P), 0x401F));
            P += __builtin_bit_cast(float,
                 __builtin_amdgcn_ds_bpermute(bp32, __builtin_bit_cast(int, P)));
            // Now every lane holds p_{lane mod 16}.

            // y0 path (reference op order: d0 = p0 + b2[0]; y0 += d0).
            float S0 = bcast(P, 0);
            float d0 = S0 + b20v;
            y0 += d0;
            outy = (kk == lane) ? y0 : outy;

            // r = sum_s p_s * w1yd[s], 4 chains, c folded into chain 0.
            float r0 = c, r1 = 0.f, r2 = 0.f, r3 = 0.f;
            #pragma unroll
            for (int q = 0; q < 4; ++q) {
                r0 = fmaf(bcast(P, q),      w1yd[q],      r0);
                r1 = fmaf(bcast(P, 4 + q),  w1yd[4 + q],  r1);
                r2 = fmaf(bcast(P, 8 + q),  w1yd[8 + q],  r2);
                r3 = fmaf(bcast(P, 12 + q), w1yd[12 + q], r3);
            }
            v = v + ((r0 + r1) + (r2 + r3));
        }

        // One vector IEEE division per chunk, coalesced store.
        if (lane < nsteps) out[(t0 + 1 + lane) * BATCH + b] = outy / SRATE;

        xv = xv_next;
    }
}

extern "C" void kernel_launch(void* const* d_in, const int* in_sizes, int n_in,
                              void* d_out, int out_size, void* d_ws, size_t ws_size,
                              hipStream_t stream) {
    const float* x  = (const float*)d_in[0];
    const float* W1 = (const float*)d_in[1];
    const float* b1 = (const float*)d_in[2];
    const float* W2 = (const float*)d_in[3];
    const float* b2 = (const float*)d_in[4];
    float* out = (float*)d_out;

    ScaledODENetFE_kernel<<<BATCH, 64, 0, stream>>>(x, W1, b1, W2, b2, out);
}

// Round 7
// 8634.594 us; speedup vs baseline: 8.9769x; 1.0417x over previous
//
#include <hip/hip_runtime.h>

// ScaledODENetFE: forward-Euler scan, T=44100, B=32, F=1, S=16, H=64.
// One wave per batch; lane k owns hidden unit k. Latency-chain-bound.
// R6 = R3 (known-good DS reduction, bit-exact trajectory) + ONE change:
// the cross-row combine P + P^16 + P^32 + P^48 is computed as
//     (P + a) + (b + c),  a = swz_xor16(P), b = bperm_xor32(P), c = bperm_xor48(P)
// i.e. THREE INDEPENDENT DS ops issued back-to-back (one ~50-cyc DS latency
// on the chain) instead of R3's two dependent hops (~100 cyc). The add
// association equals R3's ((P+P^16) + (P^32+P^48)) bit-for-bit.
// gfx950 v_permlane16/32_swap is BANNED: R4/R5 produced identical wrong
// trajectories (absmax 1.96e-3) -> swap(P,P) does not realize the xor
// exchange on HW (likely operand tying degenerates it to a row swap).
//
// Recurrence (collapsed, rank-16):
//   z = x_t*w1x + v;  h = tanh(z)
//   p = W2^T h   (butterfly reduce-scatter, XOR basis {1,2,7,8} in-row
//                 via DPP + {16,32,48} cross-row via parallel DS)
//   v' = v + (c + sum_s p_s*(W1[1+s]/sr));  y0 += (p_0 + b2[0])

#define SRATE 44100.0f
#define T_TOTAL 44100
#define BATCH 32
#define HID 64
#define ST 16

template <int CTRL>
__device__ __forceinline__ float dppmov(float x) {
    return __builtin_bit_cast(float,
        __builtin_amdgcn_update_dpp(0, __builtin_bit_cast(int, x),
                                    CTRL, 0xF, 0xF, false));
}

__device__ __forceinline__ float bcast(float v, int lane) {
    return __builtin_bit_cast(float,
        __builtin_amdgcn_readlane(__builtin_bit_cast(int, v), lane));
}

// tanh(z) = (t-1)/(t+1), t = 2^(2z*log2e). rcp ~1 ulp, no Newton
// (validated at-output across R2/R3: error invisible vs bf16 quantization).
__device__ __forceinline__ float fast_tanh(float z) {
    z = __builtin_amdgcn_fmed3f(z, -30.f, 30.f);
    float t = __builtin_amdgcn_exp2f(z * 2.8853900817779268f);
    float r = __builtin_amdgcn_rcpf(t + 1.f);
    return (t - 1.f) * r;
}

__device__ __forceinline__ int parity(int v) { return __builtin_popcount(v) & 1; }

__global__ __launch_bounds__(64, 1)
void ScaledODENetFE_kernel(const float* __restrict__ x,
                           const float* __restrict__ W1,
                           const float* __restrict__ b1,
                           const float* __restrict__ W2,
                           const float* __restrict__ b2v,
                           float* __restrict__ out) {
    const int b = blockIdx.x;      // batch element
    const int lane = threadIdx.x;  // hidden unit k
    const int TM1 = T_TOTAL - 1;   // 44099 scan steps

    // ---- one-time precompute (lane k) ----
    float w1x = W1[lane];                       // W1[0][k]
    float w1yd[ST];
    #pragma unroll
    for (int s = 0; s < ST; ++s)
        w1yd[s] = W1[(1 + s) * HID + lane] / SRATE;

    float c = 0.f;                              // c_k = sum_s b2[s]*w1yd[s]
    #pragma unroll
    for (int s = 0; s < ST; ++s) c = fmaf(b2v[s], w1yd[s], c);

    // Dual-basis lane phis for the permuted W2 layout (XOR gens 1,2,7,8).
    const int p1 = parity(lane & 5), p2 = parity(lane & 6);
    const int p3 = (lane >> 2) & 1, p4 = (lane >> 3) & 1;
    float wA[8], wB[8];   // own row / xor1-partner row, at even slots i=2j
    #pragma unroll
    for (int j = 0; j < 8; ++j) {
        const int i = 2 * j;
        const int c1 = (i & 1) ^ p1;
        const int c2 = ((i >> 1) & 1) ^ p2;
        const int c3 = ((i >> 2) & 1) ^ p3;
        const int c4 = ((i >> 3) & 1) ^ p4;
        const int s = (c1 ? 1 : 0) ^ (c2 ? 2 : 0) ^ (c3 ? 7 : 0) ^ (c4 ? 8 : 0);
        wA[j] = W2[lane * ST + s];
        wB[j] = W2[(lane ^ 1) * ST + s];
    }

    const int bp32 = ((lane ^ 32) & 63) << 2;   // ds_bpermute byte addrs
    const int bp48 = ((lane ^ 48) & 63) << 2;
    const float b20v = b2v[0];

    float v  = b1[lane];                        // v carries b1 (y starts 0)
    float y0 = 0.f;

    if (lane == 0) out[b] = 0.f;                // row t=0 is zeros

    // Lane l holds x[(t0+l)*B + b]; prefetch one chunk ahead.
    float xv = x[min(lane, TM1 - 1) * BATCH + b];

    for (int t0 = 0; t0 < TM1; t0 += 64) {
        float xvn = x[min(t0 + 64 + lane, TM1 - 1) * BATCH + b];
        const int nsteps = min(64, TM1 - t0);
        float outy = 0.f;

        for (int kk = 0; kk < nsteps; ++kk) {
            float xt = bcast(xv, kk);           // wave-uniform sample
            float z  = fmaf(xt, w1x, v);
            float h  = fast_tanh(z);

            // Stage 1 (xor1, fused products): u1[j] = h*wA[j] + h^1*wB[j]
            float hx = dppmov<0xB1>(h);         // quad_perm [1,0,3,2]
            float u1[8];
            #pragma unroll
            for (int j = 0; j < 8; ++j) u1[j] = fmaf(hx, wB[j], h * wA[j]);

            // Stage 2 (xor2 = quad_perm [2,3,0,1]).
            float u2[4];
            #pragma unroll
            for (int m = 0; m < 4; ++m)
                u2[m] = u1[2 * m] + dppmov<0x4E>(u1[2 * m + 1]);

            // Stage 3 (xor7 = row_half_mirror).
            float u3[2];
            #pragma unroll
            for (int n = 0; n < 2; ++n)
                u3[n] = u2[2 * n] + dppmov<0x141>(u2[2 * n + 1]);

            // Stage 4 (xor8 = row_ror:8).
            float P = u3[0] + dppmov<0x128>(u3[1]);

            // Cross-row combine: three INDEPENDENT DS ops (one latency),
            // summed as (P + a) + (b + c) == R3's serial result bit-for-bit.
            int   Pi = __builtin_bit_cast(int, P);
            float a16 = __builtin_bit_cast(float,
                        __builtin_amdgcn_ds_swizzle(Pi, 0x401F));       // P^16
            float a32 = __builtin_bit_cast(float,
                        __builtin_amdgcn_ds_bpermute(bp32, Pi));        // P^32
            float a48 = __builtin_bit_cast(float,
                        __builtin_amdgcn_ds_bpermute(bp48, Pi));        // P^48
            P = (P + a16) + (a32 + a48);
            // Every lane now holds p_{lane mod 16}.

            // y0 path (reference op order: d0 = p0 + b2[0]; y0 += d0).
            float S0 = bcast(P, 0);
            float d0 = S0 + b20v;
            y0 += d0;
            outy = (kk == lane) ? y0 : outy;

            // r = sum_s p_s * w1yd[s], 4 chains, c folded into chain 0
            // (bit-exact R3 accumulation order).
            float r0 = c, r1 = 0.f, r2 = 0.f, r3 = 0.f;
            #pragma unroll
            for (int q = 0; q < 4; ++q) {
                r0 = fmaf(bcast(P, q),      w1yd[q],      r0);
                r1 = fmaf(bcast(P, 4 + q),  w1yd[4 + q],  r1);
                r2 = fmaf(bcast(P, 8 + q),  w1yd[8 + q],  r2);
                r3 = fmaf(bcast(P, 12 + q), w1yd[12 + q], r3);
            }
            v = v + ((r0 + r1) + (r2 + r3));
        }

        // One vector IEEE division per chunk, coalesced store.
        if (lane < nsteps) out[(t0 + 1 + lane) * BATCH + b] = outy / SRATE;

        xv = xvn;
    }
}

extern "C" void kernel_launch(void* const* d_in, const int* in_sizes, int n_in,
                              void* d_out, int out_size, void* d_ws, size_t ws_size,
                              hipStream_t stream) {
    const float* x  = (const float*)d_in[0];
    const float* W1 = (const float*)d_in[1];
    const float* b1 = (const float*)d_in[2];
    const float* W2 = (const float*)d_in[3];
    const float* b2 = (const float*)d_in[4];
    float* out = (float*)d_out;

    ScaledODENetFE_kernel<<<BATCH, 64, 0, stream>>>(x, W1, b1, W2, b2, out);
}